// Round 1
// baseline (846.183 us; speedup 1.0000x reference)
//
#include <hip/hip_runtime.h>
#include <hip/hip_bf16.h>
#include <cstdio>

// Problem dims
#define BS   2
#define LL   2048
#define HH   8
#define PP   64
#define NQ   300          // d_state / num queries
#define NPAD 304
#define SLICE 76          // per-wave n-slice (4*76 = 304 padded)
#define TT   128          // chunk length
#define NCH  16           // L / TT
#define DI   512
#define DKEY 1034

// ---------------------------------------------------------------------------
// Generic GEMM-NT: C[m,n] = sum_k A[m*lda+k] * B[n*ldb+k]
// 64x64 tile, 256 threads, 4x4 micro-tile. K must be a multiple of 16.
// ---------------------------------------------------------------------------
__global__ __launch_bounds__(256) void gemm_nt(
    const float* __restrict__ A, const float* __restrict__ Bm, float* __restrict__ C,
    int M, int N, int K, int lda, int ldb, int ldc)
{
    __shared__ float As[16][68];
    __shared__ float Bs[16][68];
    const int tid = threadIdx.x;
    const int tx = tid & 15, ty = tid >> 4;
    const int m0 = blockIdx.x * 64, n0 = blockIdx.y * 64;
    const int lr = tid >> 2, lk = (tid & 3) << 2;
    float acc[4][4] = {};
    for (int k0 = 0; k0 < K; k0 += 16) {
        float4 av = make_float4(0.f,0.f,0.f,0.f), bv = make_float4(0.f,0.f,0.f,0.f);
        int am = m0 + lr;
        if (am < M) av = *(const float4*)(A + (size_t)am * lda + k0 + lk);
        int bn = n0 + lr;
        if (bn < N) bv = *(const float4*)(Bm + (size_t)bn * ldb + k0 + lk);
        __syncthreads();
        As[lk+0][lr] = av.x; As[lk+1][lr] = av.y; As[lk+2][lr] = av.z; As[lk+3][lr] = av.w;
        Bs[lk+0][lr] = bv.x; Bs[lk+1][lr] = bv.y; Bs[lk+2][lr] = bv.z; Bs[lk+3][lr] = bv.w;
        __syncthreads();
        #pragma unroll
        for (int kk = 0; kk < 16; ++kk) {
            float a0 = As[kk][ty*4+0], a1 = As[kk][ty*4+1], a2 = As[kk][ty*4+2], a3 = As[kk][ty*4+3];
            float b0 = Bs[kk][tx*4+0], b1 = Bs[kk][tx*4+1], b2 = Bs[kk][tx*4+2], b3 = Bs[kk][tx*4+3];
            acc[0][0] = fmaf(a0,b0,acc[0][0]); acc[0][1] = fmaf(a0,b1,acc[0][1]);
            acc[0][2] = fmaf(a0,b2,acc[0][2]); acc[0][3] = fmaf(a0,b3,acc[0][3]);
            acc[1][0] = fmaf(a1,b0,acc[1][0]); acc[1][1] = fmaf(a1,b1,acc[1][1]);
            acc[1][2] = fmaf(a1,b2,acc[1][2]); acc[1][3] = fmaf(a1,b3,acc[1][3]);
            acc[2][0] = fmaf(a2,b0,acc[2][0]); acc[2][1] = fmaf(a2,b1,acc[2][1]);
            acc[2][2] = fmaf(a2,b2,acc[2][2]); acc[2][3] = fmaf(a2,b3,acc[2][3]);
            acc[3][0] = fmaf(a3,b0,acc[3][0]); acc[3][1] = fmaf(a3,b1,acc[3][1]);
            acc[3][2] = fmaf(a3,b2,acc[3][2]); acc[3][3] = fmaf(a3,b3,acc[3][3]);
        }
    }
    #pragma unroll
    for (int i = 0; i < 4; ++i) {
        int m = m0 + ty*4 + i;
        if (m >= M) continue;
        #pragma unroll
        for (int j = 0; j < 4; ++j) {
            int n = n0 + tx*4 + j;
            if (n < N) C[(size_t)m * ldc + n] = acc[i][j];
        }
    }
}

// ---------------------------------------------------------------------------
// dt / B / C precompute from dist. One block per (b,l) row; thread j handles
// n = j (and n = 256+j for j < 44).
// ---------------------------------------------------------------------------
__global__ __launch_bounds__(256) void dtbc_kernel(
    const float* __restrict__ dist, const float* __restrict__ zx,
    const float* __restrict__ W_bc, const float* __restrict__ W_dt,
    const float* __restrict__ dt_bias,
    float* __restrict__ dtb, float* __restrict__ Bc, float* __restrict__ Cc)
{
    const int r = blockIdx.x;           // b*LL + l
    const int tid = threadIdx.x;
    const float bb = zx[(size_t)r*DKEY + 1024];
    const float cb = zx[(size_t)r*DKEY + 1025];
    #pragma unroll
    for (int rep = 0; rep < 2; ++rep) {
        int n = rep*256 + tid;
        if (n >= NQ) break;
        const float4* dp = (const float4*)(dist + ((size_t)r*NQ + n)*16);
        float d[16];
        #pragma unroll
        for (int j = 0; j < 4; ++j) {
            float4 v = dp[j];
            d[4*j+0]=v.x; d[4*j+1]=v.y; d[4*j+2]=v.z; d[4*j+3]=v.w;
        }
        float Bv = bb, Cv = cb;
        #pragma unroll
        for (int j = 0; j < 16; ++j) {
            Bv = fmaf(d[j], W_bc[j],     Bv);
            Cv = fmaf(d[j], W_bc[16+j],  Cv);
        }
        Bc[(size_t)r*NQ + n] = Bv;
        Cc[(size_t)r*NQ + n] = Cv;
        #pragma unroll
        for (int h = 0; h < HH; ++h) {
            float s = zx[(size_t)r*DKEY + 1026 + h] + dt_bias[h];
            #pragma unroll
            for (int j = 0; j < 16; ++j) s = fmaf(d[j], W_dt[h*16+j], s);
            float dtv = (s > 20.f) ? s : log1pf(expf(s));
            dtb[((size_t)r*HH + h)*NQ + n] = dtv;
        }
    }
}

// ---------------------------------------------------------------------------
// Sweep A: intra-chunk scan from zero state. block = (dir,b,h,chunk).
// wave w handles n in [w*76, w*76+76) (padded to 304 with {dA=1,u=0,C=0}),
// lane = p. Per-step coefficients staged to LDS as float4{dA,u,C,0} and read
// with wave-uniform broadcast ds_read_b128.
// ---------------------------------------------------------------------------
__global__ __launch_bounds__(256, 2) void sweepA(
    const float* __restrict__ dtb, const float* __restrict__ Bc,
    const float* __restrict__ Cc,  const float* __restrict__ zx,
    const float* __restrict__ A_log,
    float* __restrict__ Sloc, float* __restrict__ Adec,
    float* __restrict__ yF, float* __restrict__ yB)
{
    const int bid = blockIdx.x;
    const int c = bid & 15, h = (bid >> 4) & 7, b = (bid >> 7) & 1, dir = bid >> 8;
    const int tid = threadIdx.x;
    const int p = tid & 63, w = tid >> 6;
    const float Ah = -expf(A_log[h]);
    float* __restrict__ ybuf = dir ? yB : yF;

    __shared__ float4 stg[2][NPAD];
    __shared__ float  xs[2][PP];
    __shared__ float  yred[8*256];

    float S[SLICE];
    #pragma unroll
    for (int i = 0; i < SLICE; ++i) S[i] = 0.f;
    float sdt0 = 0.f, sdt1 = 0.f;

    for (int t = 0; t < TT; ++t) {
        const int ls = c*TT + t;
        const int l  = dir ? (LL-1-ls) : ls;
        const int r  = b*LL + l;
        const int buf = t & 1;
        // --- stage ---
        {
            int n = tid;  // < 256 < NQ
            float dtv = dtb[((size_t)r*HH + h)*NQ + n];
            sdt0 += dtv;
            stg[buf][n] = make_float4(expf(dtv*Ah), dtv*Bc[(size_t)r*NQ + n],
                                      Cc[(size_t)r*NQ + n], 0.f);
            if (tid < 48) {
                int n2 = 256 + tid;
                if (n2 < NQ) {
                    float dtv2 = dtb[((size_t)r*HH + h)*NQ + n2];
                    sdt1 += dtv2;
                    stg[buf][n2] = make_float4(expf(dtv2*Ah), dtv2*Bc[(size_t)r*NQ + n2],
                                               Cc[(size_t)r*NQ + n2], 0.f);
                } else {
                    stg[buf][n2] = make_float4(1.f, 0.f, 0.f, 0.f);
                }
            }
            if (tid < PP) xs[buf][tid] = zx[(size_t)r*DKEY + 512 + h*PP + tid];
        }
        __syncthreads();
        // --- compute ---
        {
            const float xp = xs[buf][p];
            float yp = 0.f;
            const float4* sg = &stg[buf][w*SLICE];
            #pragma unroll
            for (int i = 0; i < SLICE; ++i) {
                float4 v = sg[i];                       // wave-uniform broadcast
                S[i] = fmaf(S[i], v.x, v.y * xp);
                yp   = fmaf(S[i], v.z, yp);
            }
            yred[(t & 7)*256 + w*64 + p] = yp;
        }
        if ((t & 7) == 7) {
            __syncthreads();
            #pragma unroll
            for (int rep = 0; rep < 2; ++rep) {
                int idx = rep*256 + tid;
                int sl = idx >> 6, pp2 = idx & 63;
                float sum = yred[sl*256 + pp2] + yred[sl*256 + 64 + pp2]
                          + yred[sl*256 + 128 + pp2] + yred[sl*256 + 192 + pp2];
                int ts  = t - 7 + sl;
                int ls2 = c*TT + ts;
                int l2  = dir ? (LL-1-ls2) : ls2;
                ybuf[((size_t)(b*LL + l2)*HH + h)*PP + pp2] = sum;
            }
            __syncthreads();
        }
    }
    // chunk-end state + total decay
    const size_t sbase = (((size_t)((dir*BS + b)*HH + h)*NCH + c)*NQ)*PP;
    #pragma unroll
    for (int i = 0; i < SLICE; ++i) {
        int n = w*SLICE + i;
        if (n < NQ) Sloc[sbase + (size_t)n*PP + p] = S[i];
    }
    const size_t abase = ((size_t)((dir*BS + b)*HH + h)*NCH + c)*NQ;
    Adec[abase + tid] = expf(Ah * sdt0);
    if (tid < 44) Adec[abase + 256 + tid] = expf(Ah * sdt1);
}

// ---------------------------------------------------------------------------
// Inter-chunk scan: carry[c] = state before chunk c; carry[NCH] = final state.
// ---------------------------------------------------------------------------
__global__ __launch_bounds__(256) void chunkscan(
    const float* __restrict__ Sloc, const float* __restrict__ Adec,
    const float* __restrict__ proj, float* __restrict__ carry)
{
    const int bid = blockIdx.x;          // 2400 = 32 * 75
    const int dbh = bid / 75;            // (dir*2+b)*8+h
    const int tile = bid % 75;
    const int e = tile*256 + threadIdx.x;   // < 19200
    const int n = e >> 6, p = e & 63;
    const int h = dbh & 7, b = (dbh >> 3) & 1;
    float cur = proj[((size_t)(b*NQ + n))*DI + h*PP + p];   // init state
    const size_t cbase = (size_t)dbh * (NCH+1) * NQ * PP;
    const size_t sbase = (size_t)dbh * NCH * NQ * PP;
    const size_t abase = (size_t)dbh * NCH * NQ;
    carry[cbase + e] = cur;
    #pragma unroll
    for (int cc = 0; cc < NCH; ++cc) {
        float ad = Adec[abase + (size_t)cc*NQ + n];
        cur = fmaf(cur, ad, Sloc[sbase + (size_t)cc*NQ*PP + e]);
        carry[cbase + (size_t)(cc+1)*NQ*PP + e] = cur;
    }
}

// ---------------------------------------------------------------------------
// Sweep B: y += sum_n C[l,n] * beta[l,n] * carry[p,n]
// ---------------------------------------------------------------------------
__global__ __launch_bounds__(256, 2) void sweepB(
    const float* __restrict__ dtb, const float* __restrict__ Cc,
    const float* __restrict__ A_log, const float* __restrict__ carry,
    float* __restrict__ yF, float* __restrict__ yB)
{
    const int bid = blockIdx.x;
    const int c = bid & 15, h = (bid >> 4) & 7, b = (bid >> 7) & 1, dir = bid >> 8;
    const int tid = threadIdx.x;
    const int p = tid & 63, w = tid >> 6;
    const float Ah = -expf(A_log[h]);
    float* __restrict__ ybuf = dir ? yB : yF;

    __shared__ float cstg[2][NPAD];
    __shared__ float beta[NPAD];
    __shared__ float yred[8*256];

    const size_t cbase = (((size_t)((dir*BS + b)*HH + h)*(NCH+1) + c)*NQ)*PP;
    float cr[SLICE];
    #pragma unroll
    for (int i = 0; i < SLICE; ++i) {
        int n = w*SLICE + i;
        cr[i] = (n < NQ) ? carry[cbase + (size_t)n*PP + p] : 0.f;
    }
    beta[tid] = 1.f;
    if (tid < 48) beta[256 + tid] = 1.f;
    __syncthreads();

    for (int t = 0; t < TT; ++t) {
        const int ls = c*TT + t;
        const int l  = dir ? (LL-1-ls) : ls;
        const int r  = b*LL + l;
        const int buf = t & 1;
        {
            int n = tid;
            float dtv = dtb[((size_t)r*HH + h)*NQ + n];
            float bnew = beta[n] * expf(dtv*Ah);
            beta[n] = bnew;
            cstg[buf][n] = Cc[(size_t)r*NQ + n] * bnew;
            if (tid < 48) {
                int n2 = 256 + tid;
                if (n2 < NQ) {
                    float dtv2 = dtb[((size_t)r*HH + h)*NQ + n2];
                    float b2 = beta[n2] * expf(dtv2*Ah);
                    beta[n2] = b2;
                    cstg[buf][n2] = Cc[(size_t)r*NQ + n2] * b2;
                } else {
                    cstg[buf][n2] = 0.f;
                }
            }
        }
        __syncthreads();
        {
            float yc = 0.f;
            const float4* cg = (const float4*)&cstg[buf][w*SLICE];
            #pragma unroll
            for (int i4 = 0; i4 < SLICE/4; ++i4) {
                float4 v = cg[i4];                      // wave-uniform broadcast
                yc = fmaf(v.x, cr[4*i4+0], yc);
                yc = fmaf(v.y, cr[4*i4+1], yc);
                yc = fmaf(v.z, cr[4*i4+2], yc);
                yc = fmaf(v.w, cr[4*i4+3], yc);
            }
            yred[(t & 7)*256 + w*64 + p] = yc;
        }
        if ((t & 7) == 7) {
            __syncthreads();
            #pragma unroll
            for (int rep = 0; rep < 2; ++rep) {
                int idx = rep*256 + tid;
                int sl = idx >> 6, pp2 = idx & 63;
                float sum = yred[sl*256 + pp2] + yred[sl*256 + 64 + pp2]
                          + yred[sl*256 + 128 + pp2] + yred[sl*256 + 192 + pp2];
                int ts  = t - 7 + sl;
                int ls2 = c*TT + ts;
                int l2  = dir ? (LL-1-ls2) : ls2;
                size_t yi = ((size_t)(b*LL + l2)*HH + h)*PP + pp2;
                ybuf[yi] += sum;
            }
            __syncthreads();
        }
    }
}

// ---------------------------------------------------------------------------
// Gated RMSNorm: kf = g * rsqrt(mean(g^2)+eps) * w,  g = (0.5(yF+yB)+x*D)*silu(z)
// ---------------------------------------------------------------------------
__global__ __launch_bounds__(256) void gate_rms(
    const float* __restrict__ zx, const float* __restrict__ yF,
    const float* __restrict__ yB, const float* __restrict__ Dp,
    const float* __restrict__ knw, float* __restrict__ kfn)
{
    const int r = blockIdx.x, tid = threadIdx.x;
    __shared__ float part[4];
    float g[2];
    #pragma unroll
    for (int rep = 0; rep < 2; ++rep) {
        int dcol = rep*256 + tid;
        float zv = zx[(size_t)r*DKEY + dcol];
        float xv = zx[(size_t)r*DKEY + 512 + dcol];
        float yv = 0.5f*(yF[(size_t)r*DI + dcol] + yB[(size_t)r*DI + dcol]) + xv * Dp[dcol >> 6];
        float sig = 1.f / (1.f + expf(-zv));
        g[rep] = yv * (zv * sig);
    }
    float ss = g[0]*g[0] + g[1]*g[1];
    #pragma unroll
    for (int o = 32; o; o >>= 1) ss += __shfl_xor(ss, o, 64);
    if ((tid & 63) == 0) part[tid >> 6] = ss;
    __syncthreads();
    float tot = part[0] + part[1] + part[2] + part[3];
    float scale = rsqrtf(tot * (1.f/512.f) + 1e-5f);
    #pragma unroll
    for (int rep = 0; rep < 2; ++rep) {
        int dcol = rep*256 + tid;
        kfn[(size_t)r*DI + dcol] = g[rep] * scale * knw[dcol];
    }
}

// ---------------------------------------------------------------------------
// Final-state LayerNorm: lastn[b,q,(h,p)] from 0.5*(Sf+Sb)
// ---------------------------------------------------------------------------
__global__ __launch_bounds__(512) void state_ln(
    const float* __restrict__ carry, const float* __restrict__ qw,
    const float* __restrict__ qb, float* __restrict__ lastn)
{
    const int row = blockIdx.x;          // b*NQ + q
    const int b = row / NQ, q = row % NQ;
    const int tid = threadIdx.x;         // 512
    const int h = tid >> 6, p = tid & 63;
    __shared__ float pm[8], pv[8];
    size_t iF = ((((size_t)((0*BS + b)*HH + h))*(NCH+1) + NCH)*NQ + q)*PP + p;
    size_t iB = ((((size_t)((1*BS + b)*HH + h))*(NCH+1) + NCH)*NQ + q)*PP + p;
    float v = 0.5f * (carry[iF] + carry[iB]);
    float s1 = v, s2 = v*v;
    #pragma unroll
    for (int o = 32; o; o >>= 1) { s1 += __shfl_xor(s1, o, 64); s2 += __shfl_xor(s2, o, 64); }
    if ((tid & 63) == 0) { pm[tid >> 6] = s1; pv[tid >> 6] = s2; }
    __syncthreads();
    float m = 0.f, s = 0.f;
    #pragma unroll
    for (int i = 0; i < 8; ++i) { m += pm[i]; s += pv[i]; }
    m *= (1.f/512.f);
    s = s*(1.f/512.f) - m*m;
    lastn[(size_t)row*DI + tid] = (v - m)*rsqrtf(s + 1e-5f)*qw[tid] + qb[tid];
}

// ---------------------------------------------------------------------------
extern "C" void kernel_launch(void* const* d_in, const int* in_sizes, int n_in,
                              void* d_out, int out_size, void* d_ws, size_t ws_size,
                              hipStream_t stream)
{
    const float* in_key    = (const float*)d_in[0];
    const float* in_query  = (const float*)d_in[1];
    const float* dist      = (const float*)d_in[2];
    const float* W_key     = (const float*)d_in[3];
    const float* W_query   = (const float*)d_in[4];
    const float* W_bc      = (const float*)d_in[5];
    const float* W_dt      = (const float*)d_in[6];
    const float* dt_bias   = (const float*)d_in[7];
    const float* A_log     = (const float*)d_in[8];
    const float* Dp        = (const float*)d_in[9];
    const float* W_out_key = (const float*)d_in[10];
    const float* W_out_qry = (const float*)d_in[11];
    const float* knw       = (const float*)d_in[12];
    const float* qw        = (const float*)d_in[13];
    const float* qb        = (const float*)d_in[14];
    float* out = (float*)d_out;

    float* ws = (float*)d_ws;
    size_t off = 0;
    auto alloc = [&](size_t nf) { float* pp = ws + off; off += nf; return pp; };
    float* zx    = alloc((size_t)4096*DKEY);   // zxbcdt
    float* proj  = alloc((size_t)600*DI);      // init states (b*NQ+q, h*64+p)
    float* dtb   = alloc((size_t)BS*LL*HH*NQ); // dt
    float* Bc    = alloc((size_t)BS*LL*NQ);
    float* Cc    = alloc((size_t)BS*LL*NQ);
    float* Sloc  = alloc((size_t)2*BS*HH*NCH*NQ*PP);
    float* Adec  = alloc((size_t)2*BS*HH*NCH*NQ);
    float* carry = alloc((size_t)2*BS*HH*(NCH+1)*NQ*PP);
    float* yF    = alloc((size_t)BS*LL*DI);
    float* yB    = alloc((size_t)BS*LL*DI);
    float* kfn   = alloc((size_t)4096*DI);
    float* lastn = alloc((size_t)600*DI);
    if (off * sizeof(float) > ws_size) {
        fprintf(stderr, "kernel_launch: workspace too small: need %zu bytes, have %zu\n",
                off * sizeof(float), ws_size);
        return;
    }

    dim3 blk(256);
    // K1: zxbcdt = in_key @ W_key^T   [4096 x 1034]
    gemm_nt<<<dim3(64, 17), blk, 0, stream>>>(in_key, W_key, zx, 4096, DKEY, 256, 256, 256, DKEY);
    // K2: init = in_query @ W_query^T  [600 x 512]
    gemm_nt<<<dim3(10, 8), blk, 0, stream>>>(in_query, W_query, proj, 600, DI, 256, 256, 256, DI);
    // K3: dt / B / C from dist
    dtbc_kernel<<<4096, blk, 0, stream>>>(dist, zx, W_bc, W_dt, dt_bias, dtb, Bc, Cc);
    // K4: intra-chunk scans (both directions)
    sweepA<<<512, blk, 0, stream>>>(dtb, Bc, Cc, zx, A_log, Sloc, Adec, yF, yB);
    // K5: inter-chunk scan
    chunkscan<<<2400, blk, 0, stream>>>(Sloc, Adec, proj, carry);
    // K6: carry corrections into y
    sweepB<<<512, blk, 0, stream>>>(dtb, Cc, A_log, carry, yF, yB);
    // K7: gated RMSNorm + out_key projection
    gate_rms<<<4096, blk, 0, stream>>>(zx, yF, yB, Dp, knw, kfn);
    gemm_nt<<<dim3(64, 4), blk, 0, stream>>>(kfn, W_out_key, out, 4096, 256, DI, DI, DI, 256);
    // K8: final-state LayerNorm + out_query projection
    state_ln<<<600, dim3(512), 0, stream>>>(carry, qw, qb, lastn);
    gemm_nt<<<dim3(10, 4), blk, 0, stream>>>(lastn, W_out_qry, out + (size_t)4096*256, 600, 256, DI, DI, DI, 256);
}

// Round 2
// 780.812 us; speedup vs baseline: 1.0837x; 1.0837x over previous
//
#include <hip/hip_runtime.h>
#include <hip/hip_bf16.h>
#include <cstdio>

// Problem dims
#define BS   2
#define LL   2048
#define HH   8
#define PP   64
#define NQ   300          // d_state / num queries
#define NPAD 304
#define SLICE 38          // per-wave n-slice (8 waves * 38 = 304)
#define TT   128          // chunk length
#define NCH  16           // L / TT
#define DI   512
#define DKEY 1034

// ---------------------------------------------------------------------------
// Generic GEMM-NT: C[m,n] = sum_k A[m*lda+k] * B[n*ldb+k]
// ---------------------------------------------------------------------------
__global__ __launch_bounds__(256) void gemm_nt(
    const float* __restrict__ A, const float* __restrict__ Bm, float* __restrict__ C,
    int M, int N, int K, int lda, int ldb, int ldc)
{
    __shared__ float As[16][68];
    __shared__ float Bs[16][68];
    const int tid = threadIdx.x;
    const int tx = tid & 15, ty = tid >> 4;
    const int m0 = blockIdx.x * 64, n0 = blockIdx.y * 64;
    const int lr = tid >> 2, lk = (tid & 3) << 2;
    float acc[4][4] = {};
    for (int k0 = 0; k0 < K; k0 += 16) {
        float4 av = make_float4(0.f,0.f,0.f,0.f), bv = make_float4(0.f,0.f,0.f,0.f);
        int am = m0 + lr;
        if (am < M) av = *(const float4*)(A + (size_t)am * lda + k0 + lk);
        int bn = n0 + lr;
        if (bn < N) bv = *(const float4*)(Bm + (size_t)bn * ldb + k0 + lk);
        __syncthreads();
        As[lk+0][lr] = av.x; As[lk+1][lr] = av.y; As[lk+2][lr] = av.z; As[lk+3][lr] = av.w;
        Bs[lk+0][lr] = bv.x; Bs[lk+1][lr] = bv.y; Bs[lk+2][lr] = bv.z; Bs[lk+3][lr] = bv.w;
        __syncthreads();
        #pragma unroll
        for (int kk = 0; kk < 16; ++kk) {
            float a0 = As[kk][ty*4+0], a1 = As[kk][ty*4+1], a2 = As[kk][ty*4+2], a3 = As[kk][ty*4+3];
            float b0 = Bs[kk][tx*4+0], b1 = Bs[kk][tx*4+1], b2 = Bs[kk][tx*4+2], b3 = Bs[kk][tx*4+3];
            acc[0][0] = fmaf(a0,b0,acc[0][0]); acc[0][1] = fmaf(a0,b1,acc[0][1]);
            acc[0][2] = fmaf(a0,b2,acc[0][2]); acc[0][3] = fmaf(a0,b3,acc[0][3]);
            acc[1][0] = fmaf(a1,b0,acc[1][0]); acc[1][1] = fmaf(a1,b1,acc[1][1]);
            acc[1][2] = fmaf(a1,b2,acc[1][2]); acc[1][3] = fmaf(a1,b3,acc[1][3]);
            acc[2][0] = fmaf(a2,b0,acc[2][0]); acc[2][1] = fmaf(a2,b1,acc[2][1]);
            acc[2][2] = fmaf(a2,b2,acc[2][2]); acc[2][3] = fmaf(a2,b3,acc[2][3]);
            acc[3][0] = fmaf(a3,b0,acc[3][0]); acc[3][1] = fmaf(a3,b1,acc[3][1]);
            acc[3][2] = fmaf(a3,b2,acc[3][2]); acc[3][3] = fmaf(a3,b3,acc[3][3]);
        }
    }
    #pragma unroll
    for (int i = 0; i < 4; ++i) {
        int m = m0 + ty*4 + i;
        if (m >= M) continue;
        #pragma unroll
        for (int j = 0; j < 4; ++j) {
            int n = n0 + tx*4 + j;
            if (n < N) C[(size_t)m * ldc + n] = acc[i][j];
        }
    }
}

// ---------------------------------------------------------------------------
// dt / B / C precompute. Writes packed coefficient pairs {a=exp(dt*A), u=dt*B}
// per (b,h,l,n) and C per (b,l,n), both padded to NPAD (pads: a=1,u=0,c=0).
// ---------------------------------------------------------------------------
__global__ __launch_bounds__(256) void dtbc_kernel(
    const float* __restrict__ dist, const float* __restrict__ zx,
    const float* __restrict__ W_bc, const float* __restrict__ W_dt,
    const float* __restrict__ dt_bias, const float* __restrict__ A_log,
    float2* __restrict__ pairs, float* __restrict__ Cc)
{
    const int r = blockIdx.x;           // b*LL + l
    const int b = r >> 11, l = r & 2047;
    const int tid = threadIdx.x;
    const float bb = zx[(size_t)r*DKEY + 1024];
    const float cb = zx[(size_t)r*DKEY + 1025];
    #pragma unroll
    for (int rep = 0; rep < 2; ++rep) {
        int n = rep*256 + tid;
        if (n >= NPAD) break;
        if (n < NQ) {
            const float4* dp = (const float4*)(dist + ((size_t)r*NQ + n)*16);
            float d[16];
            #pragma unroll
            for (int j = 0; j < 4; ++j) {
                float4 v = dp[j];
                d[4*j+0]=v.x; d[4*j+1]=v.y; d[4*j+2]=v.z; d[4*j+3]=v.w;
            }
            float Bv = bb, Cv = cb;
            #pragma unroll
            for (int j = 0; j < 16; ++j) {
                Bv = fmaf(d[j], W_bc[j],     Bv);
                Cv = fmaf(d[j], W_bc[16+j],  Cv);
            }
            Cc[(size_t)r*NPAD + n] = Cv;
            #pragma unroll
            for (int h = 0; h < HH; ++h) {
                float s = zx[(size_t)r*DKEY + 1026 + h] + dt_bias[h];
                #pragma unroll
                for (int j = 0; j < 16; ++j) s = fmaf(d[j], W_dt[h*16+j], s);
                float dtv = (s > 20.f) ? s : log1pf(expf(s));
                float Ah = -expf(A_log[h]);
                pairs[((size_t)(b*HH+h)*LL + l)*NPAD + n] = make_float2(expf(dtv*Ah), dtv*Bv);
            }
        } else {
            Cc[(size_t)r*NPAD + n] = 0.f;
            #pragma unroll
            for (int h = 0; h < HH; ++h)
                pairs[((size_t)(b*HH+h)*LL + l)*NPAD + n] = make_float2(1.f, 0.f);
        }
    }
}

// ---------------------------------------------------------------------------
// Per-chunk total decay: Adec[bh][c][n] = prod over chunk of a. Dir-independent.
// ---------------------------------------------------------------------------
__global__ __launch_bounds__(320) void adec_kernel(
    const float2* __restrict__ pairs, float* __restrict__ Adec)
{
    const int bid = blockIdx.x;        // bh*16 + c
    const int bh = bid >> 4, c = bid & 15;
    const int n = threadIdx.x;
    if (n >= NPAD) return;
    const float2* pr = pairs + ((size_t)bh*LL + c*TT)*NPAD + n;
    float prod = 1.f;
    for (int t = 0; t < TT; ++t) prod *= pr[(size_t)t*NPAD].x;
    Adec[((size_t)bh*NCH + c)*NPAD + n] = prod;
}

// ---------------------------------------------------------------------------
// Sweep A: intra-chunk scan from zero state. block = (dir,b,h,chunk), 512 thr.
// Wave w owns n in [w*38, w*38+38); lane = p. Coefficients come in via s_load
// (wave-uniform address) and broadcast from SGPRs inside the VALU ops.
// ---------------------------------------------------------------------------
__global__ __launch_bounds__(512, 4) void sweepA(
    const float2* __restrict__ pairs, const float* __restrict__ Cc,
    const float* __restrict__ zx,
    float* __restrict__ Sloc, float* __restrict__ yF, float* __restrict__ yB)
{
    const int bid = blockIdx.x;
    const int c = bid & 15, h = (bid >> 4) & 7, b = (bid >> 7) & 1, dir = bid >> 8;
    const int tid = threadIdx.x;
    const int p = tid & 63;
    const int w = __builtin_amdgcn_readfirstlane(tid >> 6);
    const int n0 = w * SLICE;                       // wave-uniform
    float* __restrict__ ybuf = dir ? yB : yF;

    __shared__ float yred[8*512];

    float S[SLICE];
    #pragma unroll
    for (int i = 0; i < SLICE; ++i) S[i] = 0.f;

    const size_t prow = (size_t)(b*HH + h) * LL;    // pairs row base (in l)
    int l0 = dir ? (LL-1 - c*TT) : c*TT;
    float xp = zx[(size_t)(b*LL + l0)*DKEY + 512 + h*PP + p];

    for (int t = 0; t < TT; ++t) {
        const int ls = c*TT + t;
        const int l  = dir ? (LL-1-ls) : ls;
        // prefetch next step's x
        float xnext = 0.f;
        if (t + 1 < TT) {
            int l2 = dir ? (l - 1) : (l + 1);
            xnext = zx[(size_t)(b*LL + l2)*DKEY + 512 + h*PP + p];
        }
        const float2* __restrict__ pr = pairs + ((prow + l)*NPAD) + n0;      // uniform
        const float*  __restrict__ cw = Cc + ((size_t)(b*LL + l)*NPAD) + n0; // uniform
        float yp = 0.f;
        #pragma unroll
        for (int i = 0; i < SLICE; ++i) {
            float2 au = pr[i];          // s_load: a,u broadcast via SGPR
            float  cv = cw[i];          // s_load
            S[i] = fmaf(S[i], au.x, au.y * xp);
            yp   = fmaf(S[i], cv, yp);
        }
        yred[(t & 7)*512 + tid] = yp;
        if ((t & 7) == 7) {
            __syncthreads();
            int sl = tid >> 6, pp2 = tid & 63;
            float sum = 0.f;
            #pragma unroll
            for (int wv = 0; wv < 8; ++wv) sum += yred[sl*512 + wv*64 + pp2];
            int ts  = t - 7 + sl;
            int ls2 = c*TT + ts;
            int l2  = dir ? (LL-1-ls2) : ls2;
            ybuf[((size_t)(b*LL + l2)*HH + h)*PP + pp2] = sum;
            __syncthreads();
        }
        xp = xnext;
    }
    // chunk-end state
    const size_t sbase = (((size_t)((dir*BS + b)*HH + h)*NCH + c)*NQ)*PP;
    #pragma unroll
    for (int i = 0; i < SLICE; ++i) {
        int n = n0 + i;
        if (n < NQ) Sloc[sbase + (size_t)n*PP + p] = S[i];
    }
}

// ---------------------------------------------------------------------------
// Inter-chunk scan: carry[c] = state before chunk c; carry[NCH] = final state.
// Adec is direction-shared: bwd chunk cc uses fwd chunk (NCH-1-cc).
// ---------------------------------------------------------------------------
__global__ __launch_bounds__(256) void chunkscan(
    const float* __restrict__ Sloc, const float* __restrict__ Adec,
    const float* __restrict__ proj, float* __restrict__ carry)
{
    const int bid = blockIdx.x;          // 2400 = 32 * 75
    const int dbh = bid / 75;            // dir*16 + b*8 + h
    const int tile = bid % 75;
    const int e = tile*256 + threadIdx.x;   // < 19200
    const int n = e >> 6, p = e & 63;
    const int h = dbh & 7, b = (dbh >> 3) & 1, dir = dbh >> 4;
    const int bh = dbh & 15;
    float cur = proj[((size_t)(b*NQ + n))*DI + h*PP + p];   // init state
    const size_t cbase = (size_t)dbh * (NCH+1) * NQ * PP;
    const size_t sbase = (size_t)dbh * NCH * NQ * PP;
    carry[cbase + e] = cur;
    #pragma unroll
    for (int cc = 0; cc < NCH; ++cc) {
        int cF = dir ? (NCH-1-cc) : cc;
        float ad = Adec[((size_t)bh*NCH + cF)*NPAD + n];
        cur = fmaf(cur, ad, Sloc[sbase + (size_t)cc*NQ*PP + e]);
        carry[cbase + (size_t)(cc+1)*NQ*PP + e] = cur;
    }
}

// ---------------------------------------------------------------------------
// Sweep B: y += sum_n C[l,n] * beta[l,n] * carry[n,p], with beta folded into
// the carry registers (cr *= a each step).
// ---------------------------------------------------------------------------
__global__ __launch_bounds__(512, 4) void sweepB(
    const float2* __restrict__ pairs, const float* __restrict__ Cc,
    const float* __restrict__ carry,
    float* __restrict__ yF, float* __restrict__ yB)
{
    const int bid = blockIdx.x;
    const int c = bid & 15, h = (bid >> 4) & 7, b = (bid >> 7) & 1, dir = bid >> 8;
    const int tid = threadIdx.x;
    const int p = tid & 63;
    const int w = __builtin_amdgcn_readfirstlane(tid >> 6);
    const int n0 = w * SLICE;
    float* __restrict__ ybuf = dir ? yB : yF;

    __shared__ float yred[8*512];

    const size_t cbase = (((size_t)((dir*BS + b)*HH + h)*(NCH+1) + c)*NQ)*PP;
    float cr[SLICE];
    #pragma unroll
    for (int i = 0; i < SLICE; ++i) {
        int n = n0 + i;
        cr[i] = (n < NQ) ? carry[cbase + (size_t)n*PP + p] : 0.f;
    }

    const size_t prow = (size_t)(b*HH + h) * LL;

    for (int t = 0; t < TT; ++t) {
        const int ls = c*TT + t;
        const int l  = dir ? (LL-1-ls) : ls;
        const float2* __restrict__ pr = pairs + ((prow + l)*NPAD) + n0;      // uniform
        const float*  __restrict__ cw = Cc + ((size_t)(b*LL + l)*NPAD) + n0; // uniform
        float yc = 0.f;
        #pragma unroll
        for (int i = 0; i < SLICE; ++i) {
            float a  = pr[i].x;         // s_load
            float cv = cw[i];           // s_load
            cr[i] *= a;                 // fold decay into carry
            yc = fmaf(cr[i], cv, yc);
        }
        yred[(t & 7)*512 + tid] = yc;
        if ((t & 7) == 7) {
            __syncthreads();
            int sl = tid >> 6, pp2 = tid & 63;
            float sum = 0.f;
            #pragma unroll
            for (int wv = 0; wv < 8; ++wv) sum += yred[sl*512 + wv*64 + pp2];
            int ts  = t - 7 + sl;
            int ls2 = c*TT + ts;
            int l2  = dir ? (LL-1-ls2) : ls2;
            size_t yi = ((size_t)(b*LL + l2)*HH + h)*PP + pp2;
            ybuf[yi] += sum;
            __syncthreads();
        }
    }
}

// ---------------------------------------------------------------------------
// Gated RMSNorm: kf = g * rsqrt(mean(g^2)+eps) * w,  g = (0.5(yF+yB)+x*D)*silu(z)
// ---------------------------------------------------------------------------
__global__ __launch_bounds__(256) void gate_rms(
    const float* __restrict__ zx, const float* __restrict__ yF,
    const float* __restrict__ yB, const float* __restrict__ Dp,
    const float* __restrict__ knw, float* __restrict__ kfn)
{
    const int r = blockIdx.x, tid = threadIdx.x;
    __shared__ float part[4];
    float g[2];
    #pragma unroll
    for (int rep = 0; rep < 2; ++rep) {
        int dcol = rep*256 + tid;
        float zv = zx[(size_t)r*DKEY + dcol];
        float xv = zx[(size_t)r*DKEY + 512 + dcol];
        float yv = 0.5f*(yF[(size_t)r*DI + dcol] + yB[(size_t)r*DI + dcol]) + xv * Dp[dcol >> 6];
        float sig = 1.f / (1.f + expf(-zv));
        g[rep] = yv * (zv * sig);
    }
    float ss = g[0]*g[0] + g[1]*g[1];
    #pragma unroll
    for (int o = 32; o; o >>= 1) ss += __shfl_xor(ss, o, 64);
    if ((tid & 63) == 0) part[tid >> 6] = ss;
    __syncthreads();
    float tot = part[0] + part[1] + part[2] + part[3];
    float scale = rsqrtf(tot * (1.f/512.f) + 1e-5f);
    #pragma unroll
    for (int rep = 0; rep < 2; ++rep) {
        int dcol = rep*256 + tid;
        kfn[(size_t)r*DI + dcol] = g[rep] * scale * knw[dcol];
    }
}

// ---------------------------------------------------------------------------
// Final-state LayerNorm: lastn[b,q,(h,p)] from 0.5*(Sf+Sb)
// ---------------------------------------------------------------------------
__global__ __launch_bounds__(512) void state_ln(
    const float* __restrict__ carry, const float* __restrict__ qw,
    const float* __restrict__ qb, float* __restrict__ lastn)
{
    const int row = blockIdx.x;          // b*NQ + q
    const int b = row / NQ, q = row % NQ;
    const int tid = threadIdx.x;         // 512
    const int h = tid >> 6, p = tid & 63;
    __shared__ float pm[8], pv[8];
    size_t iF = ((((size_t)((0*BS + b)*HH + h))*(NCH+1) + NCH)*NQ + q)*PP + p;
    size_t iB = ((((size_t)((1*BS + b)*HH + h))*(NCH+1) + NCH)*NQ + q)*PP + p;
    float v = 0.5f * (carry[iF] + carry[iB]);
    float s1 = v, s2 = v*v;
    #pragma unroll
    for (int o = 32; o; o >>= 1) { s1 += __shfl_xor(s1, o, 64); s2 += __shfl_xor(s2, o, 64); }
    if ((tid & 63) == 0) { pm[tid >> 6] = s1; pv[tid >> 6] = s2; }
    __syncthreads();
    float m = 0.f, s = 0.f;
    #pragma unroll
    for (int i = 0; i < 8; ++i) { m += pm[i]; s += pv[i]; }
    m *= (1.f/512.f);
    s = s*(1.f/512.f) - m*m;
    lastn[(size_t)row*DI + tid] = (v - m)*rsqrtf(s + 1e-5f)*qw[tid] + qb[tid];
}

// ---------------------------------------------------------------------------
extern "C" void kernel_launch(void* const* d_in, const int* in_sizes, int n_in,
                              void* d_out, int out_size, void* d_ws, size_t ws_size,
                              hipStream_t stream)
{
    const float* in_key    = (const float*)d_in[0];
    const float* in_query  = (const float*)d_in[1];
    const float* dist      = (const float*)d_in[2];
    const float* W_key     = (const float*)d_in[3];
    const float* W_query   = (const float*)d_in[4];
    const float* W_bc      = (const float*)d_in[5];
    const float* W_dt      = (const float*)d_in[6];
    const float* dt_bias   = (const float*)d_in[7];
    const float* A_log     = (const float*)d_in[8];
    const float* Dp        = (const float*)d_in[9];
    const float* W_out_key = (const float*)d_in[10];
    const float* W_out_qry = (const float*)d_in[11];
    const float* knw       = (const float*)d_in[12];
    const float* qw        = (const float*)d_in[13];
    const float* qb        = (const float*)d_in[14];
    float* out = (float*)d_out;

    float* ws = (float*)d_ws;
    size_t off = 0;
    auto alloc = [&](size_t nf) { float* pp = ws + off; off += nf; return pp; };
    float*  zx    = alloc((size_t)4096*DKEY);             // 4.24M
    float*  proj  = alloc((size_t)600*DI);                // 0.31M
    float2* pairs = (float2*)alloc((size_t)16*LL*NPAD*2); // 19.9M floats
    float*  Cc    = alloc((size_t)BS*LL*NPAD);            // 1.25M
    float*  Sloc  = alloc((size_t)32*NCH*NQ*PP);          // 9.83M
    float*  Adec  = alloc((size_t)16*NCH*NPAD);           // 78K
    float*  carry = alloc((size_t)32*(NCH+1)*NQ*PP);      // 10.4M
    float*  yF    = alloc((size_t)BS*LL*DI);              // 2.1M
    float*  yB    = alloc((size_t)BS*LL*DI);              // 2.1M
    float*  kfn   = alloc((size_t)4096*DI);               // 2.1M
    float*  lastn = alloc((size_t)600*DI);                // 0.31M
    if (off * sizeof(float) > ws_size) {
        fprintf(stderr, "kernel_launch: workspace too small: need %zu bytes, have %zu\n",
                off * sizeof(float), ws_size);
        return;
    }

    dim3 blk(256);
    // K1: zxbcdt = in_key @ W_key^T   [4096 x 1034]
    gemm_nt<<<dim3(64, 17), blk, 0, stream>>>(in_key, W_key, zx, 4096, DKEY, 256, 256, 256, DKEY);
    // K2: init = in_query @ W_query^T  [600 x 512]
    gemm_nt<<<dim3(10, 8), blk, 0, stream>>>(in_query, W_query, proj, 600, DI, 256, 256, 256, DI);
    // K3: coefficient precompute
    dtbc_kernel<<<4096, blk, 0, stream>>>(dist, zx, W_bc, W_dt, dt_bias, A_log, pairs, Cc);
    // K3b: per-chunk decay products (dir-shared)
    adec_kernel<<<256, dim3(320), 0, stream>>>(pairs, Adec);
    // K4: intra-chunk scans (both directions)
    sweepA<<<512, dim3(512), 0, stream>>>(pairs, Cc, zx, Sloc, yF, yB);
    // K5: inter-chunk scan
    chunkscan<<<2400, blk, 0, stream>>>(Sloc, Adec, proj, carry);
    // K6: carry corrections into y
    sweepB<<<512, dim3(512), 0, stream>>>(pairs, Cc, carry, yF, yB);
    // K7: gated RMSNorm + out_key projection
    gate_rms<<<4096, blk, 0, stream>>>(zx, yF, yB, Dp, knw, kfn);
    gemm_nt<<<dim3(64, 4), blk, 0, stream>>>(kfn, W_out_key, out, 4096, 256, DI, DI, DI, 256);
    // K8: final-state LayerNorm + out_query projection
    state_ln<<<600, dim3(512), 0, stream>>>(carry, qw, qb, lastn);
    gemm_nt<<<dim3(10, 4), blk, 0, stream>>>(lastn, W_out_qry, out + (size_t)4096*256, 600, 256, DI, DI, DI, 256);
}